// Round 4
// baseline (4082.785 us; speedup 1.0000x reference)
//
#include <hip/hip_runtime.h>

// Conv2d: input (64,8,256,256) f32, filter (8,8,3,3) OIHW, VALID, stride 1.
// out (64,8,254,254) f32.
//
// Round-4 = r1's traffic-proven geometry + r2's lean compute:
//  - grid(4,16,64) NATURAL order (no swizzle — r3's bid swizzle caused 45x
//    traffic amplification; r1/r2 natural order measured clean).
//  - Block = 64x16 output tile, one n, all 8 m. Lane map & store loop are
//    verbatim r1 (measured WRITE_SIZE 141 MB = 1.07x).
//  - NO input LDS: direct global float4/float2 loads; intra-block overlap
//    dedupes in L1/L2 (r2 measured FETCH 176 MB). Kills r1's 41 KB LDS
//    occupancy cap and its 1.3e7 LDS bank-conflict cycles.
//  - LDS holds only the filter, packed [c][r][mg][m4][s] so each (c,r) is
//    3 broadcast ds_read_b128 (wave-uniform: mg is constant per wave).
//  - Thread = 8 consecutive x-px at one (n,y) x 4 output channels (mg half).

__global__ __launch_bounds__(256, 6)
void conv2d_hybrid_kernel(const float* __restrict__ inp,
                          const float* __restrict__ filt,
                          float* __restrict__ out) {
    __shared__ float s_f[576];   // [c][r][mg][m4][s] : ((c*3+r)*2+mg)*12 + m4*3 + s

    const int tid = threadIdx.x;
    for (int i = tid; i < 576; i += 256) {      // global OIHW: i = (m*8+c)*9+r*3+s
        int m = i / 72;
        int c = (i / 9) % 8;
        int r = (i / 3) % 3;
        int s = i % 3;
        s_f[((c * 3 + r) * 2 + (m >> 2)) * 12 + (m & 3) * 3 + s] = filt[i];
    }
    __syncthreads();

    const int tx = blockIdx.x;        // 4 x-tiles of 64
    const int ty = blockIdx.y;        // 16 y-tiles of 16
    const int n  = blockIdx.z;        // 64 images

    const int xg = tid & 7;           // 8 x-groups of 8 px
    const int py = (tid >> 3) & 15;   // row within tile
    const int mg = tid >> 7;          // m-half (wave-uniform)
    const int x0 = tx * 64 + xg * 8;  // 0..248
    const int y  = ty * 16 + py;      // 0..255

    if (y >= 254) return;             // after the single barrier

    const float* in_n = inp + (size_t)n * (8 * 256 * 256);

    float acc[4][8];
    #pragma unroll
    for (int m4 = 0; m4 < 4; ++m4)
        #pragma unroll
        for (int i = 0; i < 8; ++i) acc[m4][i] = 0.0f;

    // tail (x0=248): read iv[8..9] from x=254,255 instead of OOB 256,257;
    // they only feed outputs x>=254 which are never stored.
    const int o2 = (x0 <= 246) ? 8 : 6;

    #pragma unroll
    for (int c = 0; c < 8; ++c) {
        const float* ip = in_n + ((c * 256 + y) * 256 + x0);
        #pragma unroll
        for (int r = 0; r < 3; ++r) {
            float iv[10];
            const float4 v0 = *(const float4*)(ip + r * 256);       // 32B-aligned
            const float4 v1 = *(const float4*)(ip + r * 256 + 4);
            iv[0] = v0.x; iv[1] = v0.y; iv[2] = v0.z; iv[3] = v0.w;
            iv[4] = v1.x; iv[5] = v1.y; iv[6] = v1.z; iv[7] = v1.w;
            const float2 v2 = *(const float2*)(ip + r * 256 + o2);  // 8B-aligned
            iv[8] = v2.x; iv[9] = v2.y;

            float fr[12];
            const float* fp = &s_f[((c * 3 + r) * 2 + mg) * 12];
            #pragma unroll
            for (int j = 0; j < 12; ++j) fr[j] = fp[j];             // 3x broadcast b128

            #pragma unroll
            for (int s = 0; s < 3; ++s) {
                #pragma unroll
                for (int m4 = 0; m4 < 4; ++m4) {
                    const float fv = fr[m4 * 3 + s];
                    #pragma unroll
                    for (int i = 0; i < 8; ++i)
                        acc[m4][i] = fmaf(iv[i + s], fv, acc[m4][i]);
                }
            }
        }
    }

    // ---- store: verbatim r1 pattern (measured 141 MB = 1.07x) ----
    const int oy  = y;
    const int ox0 = x0;
    {
        #pragma unroll
        for (int m4 = 0; m4 < 4; ++m4) {
            float* op = out + ((((size_t)n * 8 + mg * 4 + m4) * 254 + oy) * 254 + ox0);
            if (ox0 + 8 <= 254) {
                #pragma unroll
                for (int i = 0; i < 8; ++i) op[i] = acc[m4][i];
            } else {
                #pragma unroll
                for (int i = 0; i < 8; ++i)
                    if (ox0 + i < 254) op[i] = acc[m4][i];
            }
        }
    }
}

extern "C" void kernel_launch(void* const* d_in, const int* in_sizes, int n_in,
                              void* d_out, int out_size, void* d_ws, size_t ws_size,
                              hipStream_t stream) {
    const float* inp  = (const float*)d_in[0];   // (64,8,256,256)
    const float* filt = (const float*)d_in[1];   // (8,8,3,3)
    float* outp = (float*)d_out;                 // (64,8,254,254)

    dim3 grid(4, 16, 64);
    dim3 block(256);
    conv2d_hybrid_kernel<<<grid, block, 0, stream>>>(inp, filt, outp);
}